// Round 1
// baseline (43.922 us; speedup 1.0000x reference)
//
#include <hip/hip_runtime.h>

#define FEPS 1e-16f
#define LOG_2PI 1.8378770664093453f
#define DUMMYV -4.605170185988091f   /* -2*log(10) */

constexpr int B = 32, N = 1024, V = 512, D = 4;

constexpr long long OFF_LOGPROB    = 0;
constexpr long long OFF_VOTEPRES   = 1;                                   // B*V
constexpr long long OFF_WINNER     = OFF_VOTEPRES + (long long)B * V;     // B*N*D
constexpr long long OFF_WINNERPRES = OFF_WINNER + (long long)B * N * D;   // B*N
constexpr long long OFF_ISFROM     = OFF_WINNERPRES + (long long)B * N;   // B*N
constexpr long long OFF_MLOGITS    = OFF_ISFROM + (long long)B * N;       // B*(V+1)
constexpr long long OFF_MLOGPROB   = OFF_MLOGITS + (long long)B * (V + 1);// B*(V+1)
constexpr long long OFF_ZW         = OFF_MLOGPROB + (long long)B * (V + 1);// B*N*D zeros
constexpr long long OFF_ZWP        = OFF_ZW + (long long)B * N * D;       // B*N zeros
constexpr long long OFF_PMP        = OFF_ZWP + (long long)B * N;          // B*N*V

__global__ __launch_bounds__(256) void k_mixing(const float* __restrict__ vpp,
                                                float* __restrict__ out) {
    int b = blockIdx.x;
    int t = threadIdx.x;
    __shared__ float s_ml[V + 1];
    __shared__ float red[4];

    for (int v = t; v < V; v += 256)
        s_ml[v] = logf(vpp[(long long)b * V + v] + FEPS);
    if (t == 0) s_ml[V] = DUMMYV;
    __syncthreads();

    int w = t >> 6, lane = t & 63;
    float m = -1e30f;
    for (int v = t; v < V + 1; v += 256) m = fmaxf(m, s_ml[v]);
    #pragma unroll
    for (int o = 32; o > 0; o >>= 1) m = fmaxf(m, __shfl_xor(m, o));
    if (lane == 0) red[w] = m;
    __syncthreads();
    float M = fmaxf(fmaxf(red[0], red[1]), fmaxf(red[2], red[3]));
    __syncthreads();

    float s = 0.f;
    for (int v = t; v < V + 1; v += 256) s += expf(s_ml[v] - M);
    #pragma unroll
    for (int o = 32; o > 0; o >>= 1) s += __shfl_xor(s, o);
    if (lane == 0) red[w] = s;
    __syncthreads();
    float lse = M + logf(red[0] + red[1] + red[2] + red[3]);

    for (int v = t; v < V + 1; v += 256) {
        float ml = s_ml[v];
        out[OFF_MLOGITS + (long long)b * (V + 1) + v]  = ml;
        out[OFF_MLOGPROB + (long long)b * (V + 1) + v] = ml - lse;
        if (v < V)
            out[OFF_VOTEPRES + (long long)b * V + v] = (ml > DUMMYV) ? 1.0f : 0.0f;
    }
}

__global__ __launch_bounds__(256) void k_main(const float* __restrict__ x,
                                              const float* __restrict__ votes,
                                              const float* __restrict__ scales,
                                              const float* __restrict__ vpp,
                                              const float* __restrict__ presence,
                                              const int* __restrict__ nv_p,
                                              float* __restrict__ out,
                                              float* __restrict__ ws_partial) {
    __shared__ float svx[V], svy[V], svz[V], svw[V];
    __shared__ float sh[V], sc[V], svp[V];
    __shared__ float s_dummy;
    __shared__ float s_part[4];

    int b = blockIdx.y;
    int t = threadIdx.x;
    int w = t >> 6, lane = t & 63;

    const float* mlp = out + OFF_MLOGPROB + (long long)b * (V + 1);

    for (int v = t; v < V; v += 256) {
        float4 vt = reinterpret_cast<const float4*>(votes)[(long long)b * V + v];
        float sv  = scales[(long long)b * V + v];
        float inv = 1.0f / sv;
        svx[v] = vt.x; svy[v] = vt.y; svz[v] = vt.z; svw[v] = vt.w;
        sh[v]  = 0.5f * inv * inv;
        sc[v]  = mlp[v] - 4.0f * logf(sv) - 2.0f * LOG_2PI;
        svp[v] = vpp[(long long)b * V + v];
    }
    if (t == 0) s_dummy = mlp[V] + DUMMYV;
    __syncthreads();

    int nv = nv_p[0];
    float dummy_post = s_dummy;
    float acc = 0.f;   // only lane 0's value is used

    for (int iter = 0; iter < 4; ++iter) {
        int n = blockIdx.x * 16 + iter * 4 + w;
        float4 xv = reinterpret_cast<const float4*>(x)[(long long)b * N + n];

        float p[8];
        float bv = -1e30f;
        int bi = 0;
        #pragma unroll
        for (int k = 0; k < 8; ++k) {
            int v = k * 64 + lane;
            float dx = xv.x - svx[v];
            float dy = xv.y - svy[v];
            float dz = xv.z - svz[v];
            float dw = xv.w - svw[v];
            float d2 = dx * dx + dy * dy + dz * dz + dw * dw;
            float pv = sc[v] - sh[v] * d2;
            p[k] = pv;
            if (pv > bv) { bv = pv; bi = v; }   // strict > keeps lowest idx in-lane
        }
        // cross-lane argmax + max (tie -> lowest index, matching jnp.argmax)
        #pragma unroll
        for (int o = 32; o > 0; o >>= 1) {
            float ov = __shfl_xor(bv, o);
            int   oi = __shfl_xor(bi, o);
            if (ov > bv || (ov == bv && oi < bi)) { bv = ov; bi = oi; }
        }

        float M2 = fmaxf(bv, dummy_post);
        float e[8];
        float lsum = 0.f;
        #pragma unroll
        for (int k = 0; k < 8; ++k) { e[k] = __expf(p[k] - M2); lsum += e[k]; }
        #pragma unroll
        for (int o = 32; o > 0; o >>= 1) lsum += __shfl_xor(lsum, o);
        float total = lsum + __expf(dummy_post - M2);
        float rtot  = 1.0f / total;

        long long base = OFF_PMP + ((long long)b * N + n) * V;
        #pragma unroll
        for (int k = 0; k < 8; ++k)
            out[base + k * 64 + lane] = e[k] * rtot;

        float lse = M2 + logf(total);
        if (lane == 0) {
            long long bn = (long long)b * N + n;
            acc += lse * presence[bn];
            out[OFF_WINNER + bn * 4 + 0] = svx[bi];
            out[OFF_WINNER + bn * 4 + 1] = svy[bi];
            out[OFF_WINNER + bn * 4 + 2] = svz[bi];
            out[OFF_WINNER + bn * 4 + 3] = svw[bi];
            out[OFF_WINNERPRES + bn]     = svp[bi];
            out[OFF_ISFROM + bn]         = (float)(bi / nv);
        }
    }

    if (lane == 0) s_part[w] = acc;
    __syncthreads();
    if (t == 0)
        ws_partial[(long long)blockIdx.y * gridDim.x + blockIdx.x] =
            s_part[0] + s_part[1] + s_part[2] + s_part[3];
}

__global__ __launch_bounds__(256) void k_reduce(const float* __restrict__ ws_partial,
                                                float* __restrict__ out, int count) {
    __shared__ float sred[256];
    int t = threadIdx.x;
    float s = 0.f;
    for (int i = t; i < count; i += 256) s += ws_partial[i];
    sred[t] = s;
    __syncthreads();
    for (int o = 128; o > 0; o >>= 1) {
        if (t < o) sred[t] += sred[t + o];
        __syncthreads();
    }
    if (t == 0) out[OFF_LOGPROB] = sred[0];
}

extern "C" void kernel_launch(void* const* d_in, const int* in_sizes, int n_in,
                              void* d_out, int out_size, void* d_ws, size_t ws_size,
                              hipStream_t stream) {
    const float* x        = (const float*)d_in[0];
    const float* votes    = (const float*)d_in[1];
    const float* scales   = (const float*)d_in[2];
    const float* vpp      = (const float*)d_in[3];
    const float* presence = (const float*)d_in[4];
    const int*   nv       = (const int*)d_in[5];
    float* out = (float*)d_out;
    float* ws  = (float*)d_ws;

    // zeros_like(winner) + zeros_like(winner_pres) are contiguous -> one memset
    hipMemsetAsync((void*)(out + OFF_ZW), 0,
                   (size_t)((long long)B * N * D + (long long)B * N) * sizeof(float),
                   stream);

    k_mixing<<<B, 256, 0, stream>>>(vpp, out);

    dim3 g2(N / 16, B);
    k_main<<<g2, 256, 0, stream>>>(x, votes, scales, vpp, presence, nv, out, ws);

    k_reduce<<<1, 256, 0, stream>>>(ws, out, (N / 16) * B);
}

// Round 2
// 31.878 us; speedup vs baseline: 1.3778x; 1.3778x over previous
//
#include <hip/hip_runtime.h>

#define FEPS 1e-16f
#define LOG_2PI 1.8378770664093453f
#define DUMMYV -4.605170185988091f   /* -2*log(10) */

constexpr int B = 32, N = 1024, V = 512, D = 4;

constexpr long long OFF_LOGPROB    = 0;
constexpr long long OFF_VOTEPRES   = 1;                                   // B*V
constexpr long long OFF_WINNER     = OFF_VOTEPRES + (long long)B * V;     // B*N*D
constexpr long long OFF_WINNERPRES = OFF_WINNER + (long long)B * N * D;   // B*N
constexpr long long OFF_ISFROM     = OFF_WINNERPRES + (long long)B * N;   // B*N
constexpr long long OFF_MLOGITS    = OFF_ISFROM + (long long)B * N;       // B*(V+1)
constexpr long long OFF_MLOGPROB   = OFF_MLOGITS + (long long)B * (V + 1);// B*(V+1)
constexpr long long OFF_ZW         = OFF_MLOGPROB + (long long)B * (V + 1);// B*N*D zeros
constexpr long long OFF_ZWP        = OFF_ZW + (long long)B * N * D;       // B*N zeros
constexpr long long OFF_PMP        = OFF_ZWP + (long long)B * N;          // B*N*V

__global__ __launch_bounds__(256) void k_fused(const float* __restrict__ x,
                                               const float* __restrict__ votes,
                                               const float* __restrict__ scales,
                                               const float* __restrict__ vpp,
                                               const float* __restrict__ presence,
                                               const int* __restrict__ nv_p,
                                               float* __restrict__ out,
                                               float* __restrict__ ws_partial) {
    __shared__ float4 s_v4[V];                    // 8 KB: votes for winner lookup + reg fill
    __shared__ float s_h[V], s_cpre[V], s_lg[V], s_vpp[V];   // 8 KB
    __shared__ float s_redm[4], s_reds[4], s_part[4];

    int b = blockIdx.y;
    int t = threadIdx.x;
    int w = t >> 6, lane = t & 63;

    // ---- stage votes + per-vote constants; compute mixing logits ----
    float lgv[2];
    #pragma unroll
    for (int i = 0; i < 2; ++i) {
        int v = t + i * 256;
        float4 vt = reinterpret_cast<const float4*>(votes)[(long long)b * V + v];
        float sv  = scales[(long long)b * V + v];
        float pp  = vpp[(long long)b * V + v];
        float lg  = logf(pp + FEPS);
        float inv = 1.0f / sv;
        s_v4[v]   = vt;
        s_vpp[v]  = pp;
        s_lg[v]   = lg;
        s_h[v]    = 0.5f * inv * inv;
        s_cpre[v] = lg - 4.0f * logf(sv) - 2.0f * LOG_2PI;   // mixing logit + Gauss const (lse later)
        lgv[i] = lg;
    }
    __syncthreads();

    // ---- block log-sum-exp over 513 mixing logits (512 + dummy) ----
    float m = fmaxf(lgv[0], lgv[1]);
    #pragma unroll
    for (int o = 32; o > 0; o >>= 1) m = fmaxf(m, __shfl_xor(m, o));
    if (lane == 0) s_redm[w] = m;
    __syncthreads();
    float M = fmaxf(fmaxf(fmaxf(s_redm[0], s_redm[1]), fmaxf(s_redm[2], s_redm[3])), DUMMYV);
    float s = expf(lgv[0] - M) + expf(lgv[1] - M);
    #pragma unroll
    for (int o = 32; o > 0; o >>= 1) s += __shfl_xor(s, o);
    if (lane == 0) s_reds[w] = s;
    __syncthreads();
    float S = s_reds[0] + s_reds[1] + s_reds[2] + s_reds[3] + expf(DUMMYV - M);
    float lse = M + logf(S);

    // ---- register-cache this lane's 8 votes (row-invariant) ----
    float hk[8], c2k[8], hvx[8], hvy[8], hvz[8], hvw[8];
    #pragma unroll
    for (int k = 0; k < 8; ++k) {
        int v = k * 64 + lane;
        float4 vv = s_v4[v];
        float h = s_h[v];
        float c = s_cpre[v] - lse;
        float v2 = vv.x * vv.x + vv.y * vv.y + vv.z * vv.z + vv.w * vv.w;
        hk[k]  = h;
        c2k[k] = c - h * v2;
        hvx[k] = 2.0f * h * vv.x;
        hvy[k] = 2.0f * h * vv.y;
        hvz[k] = 2.0f * h * vv.z;
        hvw[k] = 2.0f * h * vv.w;
    }
    float dummy_post = DUMMYV + (DUMMYV - lse);
    int nv = nv_p[0];
    float acc = 0.f;   // lane 0 only

    #pragma unroll
    for (int iter = 0; iter < 4; ++iter) {
        int n = blockIdx.x * 16 + iter * 4 + w;
        long long bn = (long long)b * N + n;
        float4 xv = reinterpret_cast<const float4*>(x)[bn];
        float nxx2 = -(xv.x * xv.x + xv.y * xv.y + xv.z * xv.z + xv.w * xv.w);

        float p[8];
        float bv = -1e30f;
        int bi = 0;
        #pragma unroll
        for (int k = 0; k < 8; ++k) {
            float pv = fmaf(hk[k], nxx2, c2k[k]);
            pv = fmaf(hvx[k], xv.x, pv);
            pv = fmaf(hvy[k], xv.y, pv);
            pv = fmaf(hvz[k], xv.z, pv);
            pv = fmaf(hvw[k], xv.w, pv);
            p[k] = pv;
            if (pv > bv) { bv = pv; bi = k * 64 + lane; }  // strict > keeps lowest idx in-lane
        }
        #pragma unroll
        for (int o = 32; o > 0; o >>= 1) {
            float ov = __shfl_xor(bv, o);
            int   oi = __shfl_xor(bi, o);
            if (ov > bv || (ov == bv && oi < bi)) { bv = ov; bi = oi; }
        }

        float M2 = fmaxf(bv, dummy_post);
        float e[8];
        float lsum = 0.f;
        #pragma unroll
        for (int k = 0; k < 8; ++k) { e[k] = __expf(p[k] - M2); lsum += e[k]; }
        #pragma unroll
        for (int o = 32; o > 0; o >>= 1) lsum += __shfl_xor(lsum, o);
        float total = lsum + __expf(dummy_post - M2);
        float rtot  = 1.0f / total;

        long long base = OFF_PMP + bn * V;
        #pragma unroll
        for (int k = 0; k < 8; ++k)
            out[base + k * 64 + lane] = e[k] * rtot;

        if (lane == 0) {
            acc += (M2 + logf(total)) * presence[bn];
            float4 wv = s_v4[bi];
            out[OFF_WINNER + bn * 4 + 0] = wv.x;
            out[OFF_WINNER + bn * 4 + 1] = wv.y;
            out[OFF_WINNER + bn * 4 + 2] = wv.z;
            out[OFF_WINNER + bn * 4 + 3] = wv.w;
            out[OFF_WINNERPRES + bn]     = s_vpp[bi];
            out[OFF_ISFROM + bn]         = (float)(bi / nv);
        }
        if (lane == 1) {
            out[OFF_ZW + bn * 4 + 0] = 0.f;
            out[OFF_ZW + bn * 4 + 1] = 0.f;
            out[OFF_ZW + bn * 4 + 2] = 0.f;
            out[OFF_ZW + bn * 4 + 3] = 0.f;
            out[OFF_ZWP + bn]        = 0.f;
        }
    }

    if (lane == 0) s_part[w] = acc;
    __syncthreads();
    if (t == 0)
        ws_partial[(long long)b * gridDim.x + blockIdx.x] =
            s_part[0] + s_part[1] + s_part[2] + s_part[3];

    // ---- mixing outputs (one block column per b) ----
    if (blockIdx.x == 0) {
        #pragma unroll
        for (int i = 0; i < 2; ++i) {
            int v = t + i * 256;
            float ml = s_lg[v];
            out[OFF_MLOGITS  + (long long)b * (V + 1) + v] = ml;
            out[OFF_MLOGPROB + (long long)b * (V + 1) + v] = ml - lse;
            out[OFF_VOTEPRES + (long long)b * V + v]       = (ml > DUMMYV) ? 1.0f : 0.0f;
        }
        if (t == 0) {
            out[OFF_MLOGITS  + (long long)b * (V + 1) + V] = DUMMYV;
            out[OFF_MLOGPROB + (long long)b * (V + 1) + V] = DUMMYV - lse;
        }
    }
}

__global__ __launch_bounds__(256) void k_reduce(const float* __restrict__ ws_partial,
                                                float* __restrict__ out, int count) {
    __shared__ float sred[256];
    int t = threadIdx.x;
    float s = 0.f;
    for (int i = t; i < count; i += 256) s += ws_partial[i];
    sred[t] = s;
    __syncthreads();
    for (int o = 128; o > 0; o >>= 1) {
        if (t < o) sred[t] += sred[t + o];
        __syncthreads();
    }
    if (t == 0) out[OFF_LOGPROB] = sred[0];
}

extern "C" void kernel_launch(void* const* d_in, const int* in_sizes, int n_in,
                              void* d_out, int out_size, void* d_ws, size_t ws_size,
                              hipStream_t stream) {
    const float* x        = (const float*)d_in[0];
    const float* votes    = (const float*)d_in[1];
    const float* scales   = (const float*)d_in[2];
    const float* vpp      = (const float*)d_in[3];
    const float* presence = (const float*)d_in[4];
    const int*   nv       = (const int*)d_in[5];
    float* out = (float*)d_out;
    float* ws  = (float*)d_ws;

    dim3 g(N / 16, B);
    k_fused<<<g, 256, 0, stream>>>(x, votes, scales, vpp, presence, nv, out, ws);
    k_reduce<<<1, 256, 0, stream>>>(ws, out, (N / 16) * B);
}

// Round 4
// 26.764 us; speedup vs baseline: 1.6411x; 1.1911x over previous
//
#include <hip/hip_runtime.h>

typedef float v2f __attribute__((ext_vector_type(2)));

#define FEPS 1e-16f
#define LOG_2PI 1.8378770664093453f
#define DUMMYV -4.605170185988091f   /* -2*log(10) */
#define LOG2E 1.4426950408889634f
#define LN2 0.6931471805599453f

constexpr int B = 32, N = 1024, V = 512;

constexpr long long OFF_LOGPROB    = 0;
constexpr long long OFF_VOTEPRES   = 1;
constexpr long long OFF_WINNER     = OFF_VOTEPRES + (long long)B * V;
constexpr long long OFF_WINNERPRES = OFF_WINNER + (long long)B * N * 4;
constexpr long long OFF_ISFROM     = OFF_WINNERPRES + (long long)B * N;
constexpr long long OFF_MLOGITS    = OFF_ISFROM + (long long)B * N;
constexpr long long OFF_MLOGPROB   = OFF_MLOGITS + (long long)B * (V + 1);
constexpr long long OFF_ZW         = OFF_MLOGPROB + (long long)B * (V + 1);
constexpr long long OFF_ZWP        = OFF_ZW + (long long)B * N * 4;
constexpr long long OFF_PMP        = OFF_ZWP + (long long)B * N;

__device__ __forceinline__ float fexp2(float x) {
#if __has_builtin(__builtin_amdgcn_exp2f)
    return __builtin_amdgcn_exp2f(x);
#else
    return __expf(x * LN2);
#endif
}
__device__ __forceinline__ float frcp(float x) {
#if __has_builtin(__builtin_amdgcn_rcpf)
    return __builtin_amdgcn_rcpf(x);
#else
    return 1.0f / x;
#endif
}

template<int RN> __device__ __forceinline__ float dppRorF(float x) {
    return __int_as_float(__builtin_amdgcn_update_dpp(
        0, __float_as_int(x), 0x120 | RN, 0xF, 0xF, false));
}
template<int RN> __device__ __forceinline__ int dppRorI(int x) {
    return __builtin_amdgcn_update_dpp(0, x, 0x120 | RN, 0xF, 0xF, false);
}

__device__ __forceinline__ float waveMaxF(float m) {
    m = fmaxf(m, dppRorF<1>(m));
    m = fmaxf(m, dppRorF<2>(m));
    m = fmaxf(m, dppRorF<4>(m));
    m = fmaxf(m, dppRorF<8>(m));
    m = fmaxf(m, __shfl_xor(m, 16));
    m = fmaxf(m, __shfl_xor(m, 32));
    return m;
}
__device__ __forceinline__ float waveSumF(float s) {
    s += dppRorF<1>(s);
    s += dppRorF<2>(s);
    s += dppRorF<4>(s);
    s += dppRorF<8>(s);
    s += __shfl_xor(s, 16);
    s += __shfl_xor(s, 32);
    return s;
}
__device__ __forceinline__ int waveMinI(int v) {
    int o;
    o = dppRorI<1>(v); v = o < v ? o : v;
    o = dppRorI<2>(v); v = o < v ? o : v;
    o = dppRorI<4>(v); v = o < v ? o : v;
    o = dppRorI<8>(v); v = o < v ? o : v;
    o = __shfl_xor(v, 16); v = o < v ? o : v;
    o = __shfl_xor(v, 32); v = o < v ? o : v;
    return v;
}

__global__ __launch_bounds__(256) void k_fused(const float* __restrict__ x,
                                               const float* __restrict__ votes,
                                               const float* __restrict__ scales,
                                               const float* __restrict__ vpp,
                                               const float* __restrict__ presence,
                                               const int* __restrict__ nvp,
                                               float* __restrict__ out,
                                               float* __restrict__ ws) {
    __shared__ float s_part[4];
    const int b = blockIdx.y, t = threadIdx.x, w = t >> 6, lane = t & 63;
    const long long bV = (long long)b * V;
    const float4* votes4 = reinterpret_cast<const float4*>(votes) + bV;

    // ---- prologue: per-lane votes v = k*64 + lane. NOTE: every wave loads
    // ALL 512 votes, so every wave-level reduction below is already the full
    // 512-element result — no cross-wave combine (that was R3's ln(4) bug).
    float lg[8], lsv[8];
    float4 vt[8];
    #pragma unroll
    for (int k = 0; k < 8; ++k) {
        int v = k * 64 + lane;
        vt[k]  = votes4[v];
        lsv[k] = scales[bV + v];
        lg[k]  = __logf(vpp[bV + v] + FEPS);
    }

    // ---- per-wave log-sum-exp over 513 mixing logits (full result per wave) ----
    float mm = lg[0];
    #pragma unroll
    for (int k = 1; k < 8; ++k) mm = fmaxf(mm, lg[k]);
    float M = fmaxf(waveMaxF(mm), DUMMYV);
    float ss = 0.f;
    #pragma unroll
    for (int k = 0; k < 8; ++k) ss += __expf(lg[k] - M);
    float S = waveSumF(ss) + __expf(DUMMYV - M);
    float lse = M + __logf(S);
    float dummy_post = DUMMYV + (DUMMYV - lse);

    // ---- mixing outputs (blockIdx.x == 0, wave 0 only) ----
    if (blockIdx.x == 0 && w == 0) {
        #pragma unroll
        for (int k = 0; k < 8; ++k) {
            int v = k * 64 + lane;
            out[OFF_MLOGITS  + (long long)b * (V + 1) + v] = lg[k];
            out[OFF_MLOGPROB + (long long)b * (V + 1) + v] = lg[k] - lse;
            out[OFF_VOTEPRES + bV + v] = (lg[k] > DUMMYV) ? 1.0f : 0.0f;
        }
        if (lane == 0) {
            out[OFF_MLOGITS  + (long long)b * (V + 1) + V] = DUMMYV;
            out[OFF_MLOGPROB + (long long)b * (V + 1) + V] = DUMMYV - lse;
        }
    }

    // ---- per-lane constants in log2 domain, dummy_post absorbed ----
    v2f c2[4], hk[4], hvx[4], hvy[4], hvz[4], hvw[4];
    #pragma unroll
    for (int i = 0; i < 4; ++i) {
        float cc[2], kk[2], ax[2], ay[2], az[2], aw[2];
        #pragma unroll
        for (int h = 0; h < 2; ++h) {
            int k = 2 * i + h;
            float sv  = lsv[k];
            float inv = frcp(sv);
            float hh  = 0.5f * inv * inv;
            float c   = lg[k] - 4.0f * __logf(sv) - 2.0f * LOG_2PI - lse;
            float4 vv = vt[k];
            float v2  = vv.x * vv.x + vv.y * vv.y + vv.z * vv.z + vv.w * vv.w;
            cc[h] = (c - hh * v2 - dummy_post) * LOG2E;
            kk[h] = -hh * LOG2E;                 // multiplied by +|x|^2
            float g = 2.0f * hh * LOG2E;
            ax[h] = g * vv.x; ay[h] = g * vv.y; az[h] = g * vv.z; aw[h] = g * vv.w;
        }
        c2[i].x = cc[0];  c2[i].y = cc[1];
        hk[i].x = kk[0];  hk[i].y = kk[1];
        hvx[i].x = ax[0]; hvx[i].y = ax[1];
        hvy[i].x = ay[0]; hvy[i].y = ay[1];
        hvz[i].x = az[0]; hvz[i].y = az[1];
        hvw[i].x = aw[0]; hvw[i].y = aw[1];
    }

    const float4* x4 = reinterpret_cast<const float4*>(x) + (long long)b * N;
    const long long pmpB = OFF_PMP + ((long long)b * N) * V;
    int nv = nvp[0];
    float acc = 0.f;   // lane 0 only

    #pragma unroll 2
    for (int iter = 0; iter < 8; ++iter) {
        int n = blockIdx.x * 32 + iter * 4 + w;
        long long bn = (long long)b * N + n;
        float4 xv = x4[n];
        float px2 = xv.x * xv.x + xv.y * xv.y + xv.z * xv.z + xv.w * xv.w;
        v2f P2; P2.x = px2;  P2.y = px2;
        v2f Xx; Xx.x = xv.x; Xx.y = xv.x;
        v2f Xy; Xy.x = xv.y; Xy.y = xv.y;
        v2f Xz; Xz.x = xv.z; Xz.y = xv.z;
        v2f Xw; Xw.x = xv.w; Xw.y = xv.w;

        float p2s[8];
        #pragma unroll
        for (int i = 0; i < 4; ++i) {
            v2f tt = c2[i];
            tt += hk[i]  * P2;
            tt += hvx[i] * Xx;
            tt += hvy[i] * Xy;
            tt += hvz[i] * Xz;
            tt += hvw[i] * Xw;
            p2s[2 * i]     = tt.x;
            p2s[2 * i + 1] = tt.y;
        }

        // in-lane max tree, then wave max
        float t1 = fmaxf(fmaxf(p2s[0], p2s[1]), p2s[2]);
        float t2 = fmaxf(fmaxf(p2s[3], p2s[4]), p2s[5]);
        float t3 = fmaxf(fmaxf(p2s[6], p2s[7]), t1);
        float m_in = fmaxf(t2, t3);
        float Mrow = waveMaxF(m_in);

        // argmax via match: lowest k in-lane, then min flat index across lanes
        int kw = 7;
        #pragma unroll
        for (int k = 6; k >= 0; --k) kw = (p2s[k] == Mrow) ? k : kw;
        int cand = (m_in == Mrow) ? (kw * 64 + lane) : 0x7fffffff;
        int bi = waveMinI(cand);

        // fixed-shift softmax (dummy term = exp2(0) = 1)
        float e[8];
        float se = 0.f;
        #pragma unroll
        for (int k = 0; k < 8; ++k) { e[k] = fexp2(p2s[k]); se += e[k]; }
        se = waveSumF(se);
        float total = se + 1.0f;
        float rt = frcp(total);

        long long pb = pmpB + (long long)n * V;
        #pragma unroll
        for (int k = 0; k < 8; ++k)
            out[pb + k * 64 + lane] = e[k] * rt;

        if (lane == 0) {
            acc += (dummy_post + LN2 * __log2f(total)) * presence[bn];
            float4 wv = votes4[bi];
            out[OFF_WINNER + bn * 4 + 0] = wv.x;
            out[OFF_WINNER + bn * 4 + 1] = wv.y;
            out[OFF_WINNER + bn * 4 + 2] = wv.z;
            out[OFF_WINNER + bn * 4 + 3] = wv.w;
            out[OFF_WINNERPRES + bn]     = vpp[bV + bi];
            out[OFF_ISFROM + bn]         = (float)((nv == 16) ? (bi >> 4) : (bi / nv));
        }
        if (lane == 1) {
            out[OFF_ZW + bn * 4 + 0] = 0.f;
            out[OFF_ZW + bn * 4 + 1] = 0.f;
            out[OFF_ZW + bn * 4 + 2] = 0.f;
            out[OFF_ZW + bn * 4 + 3] = 0.f;
            out[OFF_ZWP + bn]        = 0.f;
        }
    }

    if (lane == 0) s_part[w] = acc;
    __syncthreads();
    if (t == 0)
        ws[(long long)b * gridDim.x + blockIdx.x] =
            s_part[0] + s_part[1] + s_part[2] + s_part[3];
}

__global__ __launch_bounds__(256) void k_reduce(const float* __restrict__ ws,
                                                float* __restrict__ out, int count) {
    __shared__ float sred[256];
    int t = threadIdx.x;
    float s = 0.f;
    for (int i = t; i < count; i += 256) s += ws[i];
    sred[t] = s;
    __syncthreads();
    for (int o = 128; o > 0; o >>= 1) {
        if (t < o) sred[t] += sred[t + o];
        __syncthreads();
    }
    if (t == 0) out[OFF_LOGPROB] = sred[0];
}

extern "C" void kernel_launch(void* const* d_in, const int* in_sizes, int n_in,
                              void* d_out, int out_size, void* d_ws, size_t ws_size,
                              hipStream_t stream) {
    const float* x        = (const float*)d_in[0];
    const float* votes    = (const float*)d_in[1];
    const float* scales   = (const float*)d_in[2];
    const float* vpp      = (const float*)d_in[3];
    const float* presence = (const float*)d_in[4];
    const int*   nv       = (const int*)d_in[5];
    float* out = (float*)d_out;
    float* ws  = (float*)d_ws;

    dim3 g(N / 32, B);
    k_fused<<<g, 256, 0, stream>>>(x, votes, scales, vpp, presence, nv, out, ws);
    k_reduce<<<1, 256, 0, stream>>>(ws, out, (N / 32) * B);
}